// Round 1
// 141.731 us; speedup vs baseline: 1.0223x; 1.0223x over previous
//
#include <hip/hip_runtime.h>
#include <math.h>

// Problem dims (fixed by setup_inputs): B=8, C=256, H=64, W=64, fp32.
#define BB 8
#define CC 256
#define HH 64
#define WW 64
#define EPS 1e-5f
#define PSCALE (1.f / 12288.f)   // 1/(H*W*3)

// ---------------------------------------------------------------------------
// K1: fused pooling, one x pass.  Also zero-inits pooled[2048] (blocks 0..7).
//   blocks [0,2048):   bc-planes -> z1 (over h), z2t (over w, stored [B,C,H])
//   blocks [2048,2560): bh units  -> z3 (over c)
// ---------------------------------------------------------------------------
__global__ __launch_bounds__(256) void pool_kernel(
    const float* __restrict__ x,
    float* __restrict__ z1max, float* __restrict__ z1mean,
    float* __restrict__ z2tmax, float* __restrict__ z2tmean,
    float* __restrict__ z3max, float* __restrict__ z3mean,
    float* __restrict__ pooled)
{
    __shared__ float smem[HH * 65 + 512];
    int blk = blockIdx.x;
    int t = threadIdx.x;

    if (blk < 8) pooled[blk * 256 + t] = 0.f;   // zero 2048 accumulators

    if (blk < BB * CC) {
        int bc = blk;
        const float4* xt4 = (const float4*)x + (size_t)bc * 1024;
        float* tile = smem;                    // [64][65]
        float* red  = smem + HH * 65;          // [512]

        #pragma unroll
        for (int i = 0; i < 4; ++i) {
            int idx = t + i * 256;
            float4 v = xt4[idx];
            int h = idx >> 4, w0 = (idx & 15) * 4;
            float* d = &tile[h * 65 + w0];
            d[0] = v.x; d[1] = v.y; d[2] = v.z; d[3] = v.w;
        }
        __syncthreads();

        {   // reduce over h (per w); t = hg*64 + w
            int w = t & 63, hg = t >> 6;
            float m = -INFINITY, s = 0.f;
            #pragma unroll
            for (int i = 0; i < 16; ++i) {
                float v = tile[(hg * 16 + i) * 65 + w];
                m = fmaxf(m, v); s += v;
            }
            red[t] = m; red[256 + t] = s;
        }
        __syncthreads();
        if (t < 64) {
            float m = red[t], s = red[256 + t];
            #pragma unroll
            for (int g = 1; g < 4; ++g) { m = fmaxf(m, red[g * 64 + t]); s += red[256 + g * 64 + t]; }
            z1max [bc * WW + t] = m;
            z1mean[bc * WW + t] = s * (1.f / 64.f);
        }
        __syncthreads();

        {   // reduce over w (per h); t = wg*64 + h
            int h = t & 63, wg = t >> 6;
            float m = -INFINITY, s = 0.f;
            #pragma unroll
            for (int i = 0; i < 16; ++i) {
                float v = tile[h * 65 + wg * 16 + i];
                m = fmaxf(m, v); s += v;
            }
            red[t] = m; red[256 + t] = s;
        }
        __syncthreads();
        if (t < 64) {
            float m = red[t], s = red[256 + t];
            #pragma unroll
            for (int g = 1; g < 4; ++g) { m = fmaxf(m, red[g * 64 + t]); s += red[256 + g * 64 + t]; }
            // transposed layout [B,C,H]: coalesced 64-float row write
            z2tmax [bc * HH + t] = m;
            z2tmean[bc * HH + t] = s * (1.f / 64.f);
        }
    } else {
        int bh = blk - BB * CC;
        int b = bh >> 6, h = bh & 63;
        int wq = t & 15, cgp = t >> 4;         // 16 w-quads x 16 c-groups

        const float4* base = (const float4*)x
            + ((size_t)b * CC * HH * WW + (size_t)h * WW) / 4 + wq;
        float4 m = make_float4(-INFINITY, -INFINITY, -INFINITY, -INFINITY);
        float4 s = make_float4(0.f, 0.f, 0.f, 0.f);
        #pragma unroll 4
        for (int i = 0; i < 16; ++i) {
            float4 v = base[(size_t)(cgp * 16 + i) * 1024];
            m.x = fmaxf(m.x, v.x); m.y = fmaxf(m.y, v.y);
            m.z = fmaxf(m.z, v.z); m.w = fmaxf(m.w, v.w);
            s.x += v.x; s.y += v.y; s.z += v.z; s.w += v.w;
        }
        float4* mred = (float4*)smem;
        float4* sred = (float4*)smem + 256;
        mred[t] = m; sred[t] = s;
        __syncthreads();
        if (t < 16) {
            float4 mm = mred[t], ss = sred[t];
            #pragma unroll
            for (int g = 1; g < 16; ++g) {
                float4 mv = mred[g * 16 + t], sv = sred[g * 16 + t];
                mm.x = fmaxf(mm.x, mv.x); mm.y = fmaxf(mm.y, mv.y);
                mm.z = fmaxf(mm.z, mv.z); mm.w = fmaxf(mm.w, mv.w);
                ss.x += sv.x; ss.y += sv.y; ss.z += sv.z; ss.w += sv.w;
            }
            ss.x *= (1.f / 256.f); ss.y *= (1.f / 256.f);
            ss.z *= (1.f / 256.f); ss.w *= (1.f / 256.f);
            *(float4*)(z3max  + bh * WW + t * 4) = mm;
            *(float4*)(z3mean + bh * WW + t * 4) = ss;
        }
    }
}

// 7x7 conv (2ch->1, zero pad) + inference BN + sigmoid -> gate value.
// TR=1 applies the transposed 7x7 taps (for data stored with swapped axes).
template<int TR>
__device__ __forceinline__ float conv_gate(
    const float* __restrict__ zm, const float* __restrict__ za,
    const float* __restrict__ wp, const float* gp, const float* bp,
    const float* mp, const float* vp,
    int R, int Cw, int b, int r, int col)
{
    const float* zmb = zm + (size_t)b * R * Cw;
    const float* zab = za + (size_t)b * R * Cw;
    float acc = 0.f;
    #pragma unroll
    for (int dr = 0; dr < 7; ++dr) {
        int rr = r + dr - 3;
        if (rr < 0 || rr >= R) continue;
        #pragma unroll
        for (int dc = 0; dc < 7; ++dc) {
            int cc2 = col + dc - 3;
            if (cc2 < 0 || cc2 >= Cw) continue;
            const int wi = TR ? (dc * 7 + dr) : (dr * 7 + dc);
            acc += wp[wi]      * zmb[rr * Cw + cc2]
                 + wp[49 + wi] * zab[rr * Cw + cc2];
        }
    }
    float scale = gp[0] * rsqrtf(vp[0] + EPS);
    float y = (acc - mp[0]) * scale + bp[0];
    return 1.f / (1.f + __expf(-y));
}

// ---------------------------------------------------------------------------
// K2: gates for all 3 branches + pooled accumulation (raw sums, atomics).
//   raw[b,c] = 64*Σ_w s1*z1mean + 64*Σ_h s2*z2tmean + Σ_{h,w} x*s3
//   blocks [0,512):     branch 0 (s1, rows=C cols=W) — wave-reduced atomic
//   blocks [512,1024):  branch 1 (s2t, rows=C cols=H, transposed taps) — same
//   blocks [1024,1536): branch 2 (s3, [H,W]) — s3 row + x·s3 pass, 4-lane reduce
// ---------------------------------------------------------------------------
__global__ __launch_bounds__(256) void gate_kernel(
    const float* __restrict__ x,
    const float* __restrict__ z1max, const float* __restrict__ z1mean,
    const float* __restrict__ w0p, const float* g0, const float* b0,
    const float* m0, const float* v0, float* __restrict__ s1,
    const float* __restrict__ z2tmax, const float* __restrict__ z2tmean,
    const float* __restrict__ w1p, const float* g1, const float* b1,
    const float* m1, const float* v1, float* __restrict__ s2,
    const float* __restrict__ z3max, const float* __restrict__ z3mean,
    const float* __restrict__ w2p, const float* g2, const float* b2,
    const float* m2, const float* v2, float* __restrict__ s3,
    float* __restrict__ pooled)
{
    int blk = blockIdx.x;
    int t = threadIdx.x;

    if (blk < 512) {
        // ---- branch 0: o over [B,C,W]; a wave = one (b,c) row of 64 w ----
        int o = blk * 256 + t;
        int b = o >> 14, rem = o & 16383;
        int r = rem >> 6, col = o & 63;
        float v = conv_gate<0>(z1max, z1mean, w0p, g0, b0, m0, v0, CC, WW, b, r, col);
        s1[o] = v;
        float prod = v * z1mean[o];
        #pragma unroll
        for (int off = 32; off >= 1; off >>= 1) prod += __shfl_down(prod, off);
        if ((t & 63) == 0) atomicAdd(&pooled[o >> 6], 64.f * prod);
    } else if (blk < 1024) {
        // ---- branch 1: o over [B,C,H]; identical structure, transposed taps --
        int o = (blk - 512) * 256 + t;
        int b = o >> 14, rem = o & 16383;
        int r = rem >> 6, col = o & 63;       // r=c, col=h
        float v = conv_gate<1>(z2tmax, z2tmean, w1p, g1, b1, m1, v1, CC, HH, b, r, col);
        s2[o] = v;                             // layout [B,C,H]
        float prod = v * z2tmean[o];
        #pragma unroll
        for (int off = 32; off >= 1; off >>= 1) prod += __shfl_down(prod, off);
        if ((t & 63) == 0) atomicAdd(&pooled[o >> 6], 64.f * prod);
    } else {
        // ---- branch 2: one block per (b,h) ----
        __shared__ float s3row[WW];
        int bh = blk - 1024;
        int b = bh >> 6, h = bh & 63;
        if (t < 64) {
            float v = conv_gate<0>(z3max, z3mean, w2p, g2, b2, m2, v2, HH, WW, b, h, t);
            s3[bh * WW + t] = v;
            s3row[t] = v;
        }
        __syncthreads();

        // x·s3 over all 256 c for this (b,h).  Lane layout within a wave:
        //   l = c_local*4 + wsub : 16 c's x 4 w-chunks of 16.
        int wv = t >> 6, l = t & 63;
        int c_local = l >> 2, wsub = l & 3;
        const float4* s3q4 = (const float4*)s3row;    // 16 quads

        #pragma unroll 1
        for (int pass = 0; pass < 4; ++pass) {
            int c = pass * 64 + (wv << 4) + c_local;
            const float4* xr4 = (const float4*)x
                + ((size_t)(b * 256 + c) * 4096 + h * 64) / 4 + wsub * 4;
            float acc = 0.f;
            #pragma unroll
            for (int j = 0; j < 4; ++j) {
                float4 xv = xr4[j];
                float4 sv = s3q4[wsub * 4 + j];
                acc += xv.x * sv.x + xv.y * sv.y + xv.z * sv.z + xv.w * sv.w;
            }
            acc += __shfl_xor(acc, 1);
            acc += __shfl_xor(acc, 2);
            if (wsub == 0) atomicAdd(&pooled[b * 256 + c], acc);
        }
    }
}

// ---------------------------------------------------------------------------
// K3: out = x * (k0*s1[b,c,w] + k1*s2t[b,c,h] + k2*s3[b,h,w])
//     softmax weights from raw pooled sums; each block is (b,c)-uniform, so
//     compute the 21-tap conv + softmax ONCE per block and smem-broadcast.
// ---------------------------------------------------------------------------
__global__ __launch_bounds__(256) void final_kernel(
    const float* __restrict__ x,
    const float* __restrict__ s1, const float* __restrict__ s2,
    const float* __restrict__ s3, const float* __restrict__ pooled,
    const float* __restrict__ w1d, float* __restrict__ out)
{
    __shared__ float kk[3];
    int t = threadIdx.x;
    int i4 = blockIdx.x * 256 + t;                // float4 index
    int rest = i4 >> 4;                           // (b*256+c)*64 + h
    int h = rest & 63;
    int c = (rest >> 6) & 255;                    // uniform across block
    int b = rest >> 14;                           // uniform across block

    if (t == 0) {
        float lg0 = 0.f, lg1 = 0.f, lg2 = 0.f;
        #pragma unroll
        for (int jj = 0; jj < 7; ++jj) {
            int cc2 = c + jj - 3;
            float pv = (cc2 >= 0 && cc2 < CC) ? pooled[b * CC + cc2] : 0.f;
            lg0 += w1d[jj] * pv;
            lg1 += w1d[7 + jj] * pv;
            lg2 += w1d[14 + jj] * pv;
        }
        lg0 *= PSCALE; lg1 *= PSCALE; lg2 *= PSCALE;
        float mx = fmaxf(lg0, fmaxf(lg1, lg2));
        float e0 = __expf(lg0 - mx), e1 = __expf(lg1 - mx), e2 = __expf(lg2 - mx);
        float inv = 1.f / (e0 + e1 + e2);
        kk[0] = e0 * inv; kk[1] = e1 * inv; kk[2] = e2 * inv;
    }
    __syncthreads();
    float k0 = kk[0], k1 = kk[1], k2 = kk[2];

    int w0 = (i4 & 15) * 4;
    const float4 x4  = *(const float4*)(x  + (size_t)i4 * 4);
    const float4 s1v = *(const float4*)(s1 + ((size_t)(b * CC + c)) * WW + w0);
    const float  s2v = s2[rest];                  // [B,C,H] — index in hand
    const float4 s3v = *(const float4*)(s3 + ((size_t)(b * HH + h)) * WW + w0);

    float4 o;
    o.x = x4.x * (k0 * s1v.x + k1 * s2v + k2 * s3v.x);
    o.y = x4.y * (k0 * s1v.y + k1 * s2v + k2 * s3v.y);
    o.z = x4.z * (k0 * s1v.z + k1 * s2v + k2 * s3v.z);
    o.w = x4.w * (k0 * s1v.w + k1 * s2v + k2 * s3v.w);
    *(float4*)(out + (size_t)i4 * 4) = o;
}

// ---------------------------------------------------------------------------
extern "C" void kernel_launch(void* const* d_in, const int* in_sizes, int n_in,
                              void* d_out, int out_size, void* d_ws, size_t ws_size,
                              hipStream_t stream)
{
    const float* x    = (const float*)d_in[0];
    const float* w_cw = (const float*)d_in[1];
    const float* g_cw = (const float*)d_in[2];
    const float* b_cw = (const float*)d_in[3];
    const float* m_cw = (const float*)d_in[4];
    const float* v_cw = (const float*)d_in[5];
    const float* w_hc = (const float*)d_in[6];
    const float* g_hc = (const float*)d_in[7];
    const float* b_hc = (const float*)d_in[8];
    const float* m_hc = (const float*)d_in[9];
    const float* v_hc = (const float*)d_in[10];
    const float* w_hw = (const float*)d_in[11];
    const float* g_hw = (const float*)d_in[12];
    const float* b_hw = (const float*)d_in[13];
    const float* m_hw = (const float*)d_in[14];
    const float* v_hw = (const float*)d_in[15];
    const float* w1d  = (const float*)d_in[16];
    float* out = (float*)d_out;

    float* ws = (float*)d_ws;
    const size_t N1 = (size_t)BB * CC * WW;   // 131072  [B,C,W]
    const size_t N2 = (size_t)BB * CC * HH;   // 131072  [B,C,H] (transposed)
    const size_t N3 = (size_t)BB * HH * WW;   // 32768   [B,H,W]
    float* z1max   = ws;
    float* z1mean  = z1max   + N1;
    float* z2tmax  = z1mean  + N1;
    float* z2tmean = z2tmax  + N2;
    float* z3max   = z2tmean + N2;
    float* z3mean  = z3max   + N3;
    float* s1      = z3mean  + N3;
    float* s2      = s1 + N1;
    float* s3      = s2 + N2;
    float* pooled  = s3 + N3;                 // B*C = 2048 raw sums

    pool_kernel<<<BB * CC + BB * HH, 256, 0, stream>>>(
        x, z1max, z1mean, z2tmax, z2tmean, z3max, z3mean, pooled);

    gate_kernel<<<1536, 256, 0, stream>>>(
        x,
        z1max, z1mean, w_cw, g_cw, b_cw, m_cw, v_cw, s1,
        z2tmax, z2tmean, w_hc, g_hc, b_hc, m_hc, v_hc, s2,
        z3max, z3mean, w_hw, g_hw, b_hw, m_hw, v_hw, s3,
        pooled);

    final_kernel<<<(BB * CC * HH * WW / 4) / 256, 256, 0, stream>>>(
        x, s1, s2, s3, pooled, w1d, out);
}

// Round 2
// 141.170 us; speedup vs baseline: 1.0263x; 1.0040x over previous
//
#include <hip/hip_runtime.h>
#include <math.h>

// Problem dims (fixed by setup_inputs): B=8, C=256, H=64, W=64, fp32.
#define BB 8
#define CC 256
#define HH 64
#define WW 64
#define EPS 1e-5f
#define PSCALE (1.f / 12288.f)   // 1/(H*W*3)

// ---------------------------------------------------------------------------
// K1: fused pooling, one x pass.  Also zero-inits pooled[2048] (blocks 0..7).
//   blocks [0,2048):   bc-planes -> z1 (over h), z2t (over w, stored [B,C,H])
//   blocks [2048,2560): bh units  -> z3 (over c)
// ---------------------------------------------------------------------------
__global__ __launch_bounds__(256) void pool_kernel(
    const float* __restrict__ x,
    float* __restrict__ z1max, float* __restrict__ z1mean,
    float* __restrict__ z2tmax, float* __restrict__ z2tmean,
    float* __restrict__ z3max, float* __restrict__ z3mean,
    float* __restrict__ pooled)
{
    __shared__ float smem[HH * 65 + 512];
    int blk = blockIdx.x;
    int t = threadIdx.x;

    if (blk < 8) pooled[blk * 256 + t] = 0.f;   // zero 2048 accumulators

    if (blk < BB * CC) {
        int bc = blk;
        const float4* xt4 = (const float4*)x + (size_t)bc * 1024;
        float* tile = smem;                    // [64][65]
        float* red  = smem + HH * 65;          // [512]

        #pragma unroll
        for (int i = 0; i < 4; ++i) {
            int idx = t + i * 256;
            float4 v = xt4[idx];
            int h = idx >> 4, w0 = (idx & 15) * 4;
            float* d = &tile[h * 65 + w0];
            d[0] = v.x; d[1] = v.y; d[2] = v.z; d[3] = v.w;
        }
        __syncthreads();

        {   // reduce over h (per w); t = hg*64 + w
            int w = t & 63, hg = t >> 6;
            float m = -INFINITY, s = 0.f;
            #pragma unroll
            for (int i = 0; i < 16; ++i) {
                float v = tile[(hg * 16 + i) * 65 + w];
                m = fmaxf(m, v); s += v;
            }
            red[t] = m; red[256 + t] = s;
        }
        __syncthreads();
        if (t < 64) {
            float m = red[t], s = red[256 + t];
            #pragma unroll
            for (int g = 1; g < 4; ++g) { m = fmaxf(m, red[g * 64 + t]); s += red[256 + g * 64 + t]; }
            z1max [bc * WW + t] = m;
            z1mean[bc * WW + t] = s * (1.f / 64.f);
        }
        __syncthreads();

        {   // reduce over w (per h); t = wg*64 + h
            int h = t & 63, wg = t >> 6;
            float m = -INFINITY, s = 0.f;
            #pragma unroll
            for (int i = 0; i < 16; ++i) {
                float v = tile[h * 65 + wg * 16 + i];
                m = fmaxf(m, v); s += v;
            }
            red[t] = m; red[256 + t] = s;
        }
        __syncthreads();
        if (t < 64) {
            float m = red[t], s = red[256 + t];
            #pragma unroll
            for (int g = 1; g < 4; ++g) { m = fmaxf(m, red[g * 64 + t]); s += red[256 + g * 64 + t]; }
            // transposed layout [B,C,H]: coalesced 64-float row write
            z2tmax [bc * HH + t] = m;
            z2tmean[bc * HH + t] = s * (1.f / 64.f);
        }
    } else {
        int bh = blk - BB * CC;
        int b = bh >> 6, h = bh & 63;
        int wq = t & 15, cgp = t >> 4;         // 16 w-quads x 16 c-groups

        const float4* base = (const float4*)x
            + ((size_t)b * CC * HH * WW + (size_t)h * WW) / 4 + wq;
        float4 m = make_float4(-INFINITY, -INFINITY, -INFINITY, -INFINITY);
        float4 s = make_float4(0.f, 0.f, 0.f, 0.f);
        #pragma unroll 4
        for (int i = 0; i < 16; ++i) {
            float4 v = base[(size_t)(cgp * 16 + i) * 1024];
            m.x = fmaxf(m.x, v.x); m.y = fmaxf(m.y, v.y);
            m.z = fmaxf(m.z, v.z); m.w = fmaxf(m.w, v.w);
            s.x += v.x; s.y += v.y; s.z += v.z; s.w += v.w;
        }
        float4* mred = (float4*)smem;
        float4* sred = (float4*)smem + 256;
        mred[t] = m; sred[t] = s;
        __syncthreads();
        if (t < 16) {
            float4 mm = mred[t], ss = sred[t];
            #pragma unroll
            for (int g = 1; g < 16; ++g) {
                float4 mv = mred[g * 16 + t], sv = sred[g * 16 + t];
                mm.x = fmaxf(mm.x, mv.x); mm.y = fmaxf(mm.y, mv.y);
                mm.z = fmaxf(mm.z, mv.z); mm.w = fmaxf(mm.w, mv.w);
                ss.x += sv.x; ss.y += sv.y; ss.z += sv.z; ss.w += sv.w;
            }
            ss.x *= (1.f / 256.f); ss.y *= (1.f / 256.f);
            ss.z *= (1.f / 256.f); ss.w *= (1.f / 256.f);
            *(float4*)(z3max  + bh * WW + t * 4) = mm;
            *(float4*)(z3mean + bh * WW + t * 4) = ss;
        }
    }
}

// ---------------------------------------------------------------------------
// K2: gates for all 3 branches + pooled accumulation (raw sums, atomics).
//   raw[b,c] = 64*Σ_w s1*z1mean + 64*Σ_h s2*z2tmean + Σ_{h,w} x*s3
//
//   blocks [0,64):     branch 0: (b, 32-row tile) of the [256c x 64w] plane
//   blocks [64,128):   branch 1: same on z2t [256c x 64h], taps transposed
//   blocks [128,640):  branch 2: one block per (b,h) — s3 + x·s3 pass
//
//   Branches 0/1: LDS-staged 38x70 zero-padded halo tile (max+mean) + 98
//   weights; each thread computes 8 outputs (rows rt+rg*8+0..7, one col).
//   Tap order (dr asc, dc asc, max-then-mean) matches the naive loop, and
//   halo taps contribute w*0 — FP-identical to skipping them.
// ---------------------------------------------------------------------------
#define TROWS 38            // 32 + 2*3 halo
#define TPITCH 70           // 64 + 2*3 halo
#define TELEMS (TROWS * TPITCH)   // 2660

__global__ __launch_bounds__(256) void gate_kernel(
    const float* __restrict__ x,
    const float* __restrict__ z1max, const float* __restrict__ z1mean,
    const float* __restrict__ w0p, const float* g0, const float* b0,
    const float* m0, const float* v0, float* __restrict__ s1,
    const float* __restrict__ z2tmax, const float* __restrict__ z2tmean,
    const float* __restrict__ w1p, const float* g1, const float* b1,
    const float* m1, const float* v1, float* __restrict__ s2,
    const float* __restrict__ z3max, const float* __restrict__ z3mean,
    const float* __restrict__ w2p, const float* g2, const float* b2,
    const float* m2, const float* v2, float* __restrict__ s3,
    float* __restrict__ pooled)
{
    __shared__ float sm[2 * TELEMS + 100];     // 5420 floats = 21.7 KB
    int blk = blockIdx.x;
    int t = threadIdx.x;

    if (blk < 128) {
        // ---- branches 0/1: tiled 7x7 conv over a [256 x 64] plane ----
        const int br  = blk >> 6;              // 0 -> (z1,s1)  1 -> (z2t,s2)
        const int sub = blk & 63;
        const int b   = sub >> 3;
        const int rt  = (sub & 7) * 32;        // first output row of tile
        const float* zm = br ? z2tmax  : z1max;
        const float* za = br ? z2tmean : z1mean;
        const float* wp = br ? w1p : w0p;
        const float* gp = br ? g1 : g0;  const float* bp = br ? b1 : b0;
        const float* mp = br ? m1 : m0;  const float* vp = br ? v1 : v0;
        float* sout = br ? s2 : s1;

        float* tm  = sm;                       // [38][70] max tile
        float* ta  = sm + TELEMS;              // [38][70] mean tile
        float* wsm = sm + 2 * TELEMS;          // 98 taps (transposed for br=1)

        if (t < 98) {
            int p = (t >= 49) ? 1 : 0;
            int q = t - p * 49;
            wsm[t] = wp[p * 49 + (br ? (q % 7) * 7 + q / 7 : q)];
        }
        for (int idx = t; idx < TELEMS; idx += 256) {
            int r  = idx / TPITCH;
            int cc = idx - r * TPITCH;
            int grow = rt + r - 3, gcol = cc - 3;
            bool ok = (grow >= 0) & (grow < 256) & (gcol >= 0) & (gcol < 64);
            size_t gi = ((size_t)b * 256 + grow) * 64 + gcol;
            tm[idx] = ok ? zm[gi] : 0.f;
            ta[idx] = ok ? za[gi] : 0.f;
        }
        __syncthreads();

        const int col = t & 63, rg = t >> 6;   // 4 row-groups x 64 cols
        const int lo0 = rg * 8;                // first of 8 output rows

        float acc[8];
        #pragma unroll
        for (int o = 0; o < 8; ++o) acc[o] = 0.f;

        #pragma unroll
        for (int rl = 0; rl < 14; ++rl) {      // tile rows lo0 .. lo0+13
            const float* rowm = &tm[(lo0 + rl) * TPITCH + col];
            const float* rowa = &ta[(lo0 + rl) * TPITCH + col];
            #pragma unroll
            for (int dc = 0; dc < 7; ++dc) {
                float vmax = rowm[dc], vmean = rowa[dc];
                #pragma unroll
                for (int o = 0; o < 8; ++o) {
                    int dr = rl - o;
                    if (dr >= 0 && dr < 7) {
                        acc[o] = fmaf(wsm[dr * 7 + dc],      vmax,  acc[o]);
                        acc[o] = fmaf(wsm[49 + dr * 7 + dc], vmean, acc[o]);
                    }
                }
            }
        }

        const float bnscale = gp[0] * rsqrtf(vp[0] + EPS);
        const float bnmean = mp[0], bnbias = bp[0];
        #pragma unroll
        for (int o = 0; o < 8; ++o) {
            int lo = lo0 + o;                  // 0..31
            float y = (acc[o] - bnmean) * bnscale + bnbias;
            float sv = 1.f / (1.f + __expf(-y));
            sout[((size_t)b * 256 + rt + lo) * 64 + col] = sv;
            float prod = sv * ta[(lo + 3) * TPITCH + col + 3];
            #pragma unroll
            for (int off = 32; off >= 1; off >>= 1) prod += __shfl_down(prod, off);
            if ((t & 63) == 0) atomicAdd(&pooled[b * 256 + rt + lo], 64.f * prod);
        }
    } else {
        // ---- branch 2: one block per (b,h) ----
        float* t3m   = sm;                     // [7][70]
        float* t3a   = sm + 7 * TPITCH;        // [7][70]
        float* w2sm  = sm + 14 * TPITCH;       // 98
        float* s3row = sm + 14 * TPITCH + 98;  // 64

        int bh = blk - 128;
        int b = bh >> 6, h = bh & 63;

        if (t < 98) w2sm[t] = w2p[t];
        for (int idx = t; idx < 7 * TPITCH; idx += 256) {
            int r  = idx / TPITCH;
            int cc = idx - r * TPITCH;
            int grow = h + r - 3, gcol = cc - 3;
            bool ok = (grow >= 0) & (grow < 64) & (gcol >= 0) & (gcol < 64);
            size_t gi = ((size_t)b * 64 + grow) * 64 + gcol;
            t3m[idx] = ok ? z3max[gi]  : 0.f;
            t3a[idx] = ok ? z3mean[gi] : 0.f;
        }
        __syncthreads();

        if (t < 64) {
            float acc = 0.f;
            #pragma unroll
            for (int dr = 0; dr < 7; ++dr) {
                #pragma unroll
                for (int dc = 0; dc < 7; ++dc) {
                    acc = fmaf(w2sm[dr * 7 + dc],      t3m[dr * TPITCH + t + dc], acc);
                    acc = fmaf(w2sm[49 + dr * 7 + dc], t3a[dr * TPITCH + t + dc], acc);
                }
            }
            float scale = g2[0] * rsqrtf(v2[0] + EPS);
            float y = (acc - m2[0]) * scale + b2[0];
            float v = 1.f / (1.f + __expf(-y));
            s3[bh * WW + t] = v;
            s3row[t] = v;
        }
        __syncthreads();

        // x·s3 over all 256 c for this (b,h).  Lane layout within a wave:
        //   l = c_local*4 + wsub : 16 c's x 4 w-chunks of 16.
        // All 16 float4 loads hoisted -> 16 KB/wave in flight (HBM-saturating).
        int wv = t >> 6, l = t & 63;
        int c_local = l >> 2, wsub = l & 3;
        const float4* s3q4 = (const float4*)s3row;    // 16 quads

        float4 xv[16];
        #pragma unroll
        for (int pass = 0; pass < 4; ++pass) {
            int c = pass * 64 + (wv << 4) + c_local;
            const float4* xr4 = (const float4*)x
                + ((size_t)(b * 256 + c) * 4096 + h * 64) / 4 + wsub * 4;
            #pragma unroll
            for (int j = 0; j < 4; ++j) xv[pass * 4 + j] = xr4[j];
        }
        #pragma unroll
        for (int pass = 0; pass < 4; ++pass) {
            int c = pass * 64 + (wv << 4) + c_local;
            float acc = 0.f;
            #pragma unroll
            for (int j = 0; j < 4; ++j) {
                float4 a = xv[pass * 4 + j];
                float4 sv = s3q4[wsub * 4 + j];
                acc += a.x * sv.x + a.y * sv.y + a.z * sv.z + a.w * sv.w;
            }
            acc += __shfl_xor(acc, 1);
            acc += __shfl_xor(acc, 2);
            if (wsub == 0) atomicAdd(&pooled[b * 256 + c], acc);
        }
    }
}

// ---------------------------------------------------------------------------
// K3: out = x * (k0*s1[b,c,w] + k1*s2t[b,c,h] + k2*s3[b,h,w])
//     softmax weights from raw pooled sums; each block is (b,c)-uniform, so
//     compute the 21-tap conv + softmax ONCE per block and smem-broadcast.
// ---------------------------------------------------------------------------
__global__ __launch_bounds__(256) void final_kernel(
    const float* __restrict__ x,
    const float* __restrict__ s1, const float* __restrict__ s2,
    const float* __restrict__ s3, const float* __restrict__ pooled,
    const float* __restrict__ w1d, float* __restrict__ out)
{
    __shared__ float kk[3];
    int t = threadIdx.x;
    int i4 = blockIdx.x * 256 + t;                // float4 index
    int rest = i4 >> 4;                           // (b*256+c)*64 + h
    int h = rest & 63;
    int c = (rest >> 6) & 255;                    // uniform across block
    int b = rest >> 14;                           // uniform across block

    if (t == 0) {
        float lg0 = 0.f, lg1 = 0.f, lg2 = 0.f;
        #pragma unroll
        for (int jj = 0; jj < 7; ++jj) {
            int cc2 = c + jj - 3;
            float pv = (cc2 >= 0 && cc2 < CC) ? pooled[b * CC + cc2] : 0.f;
            lg0 += w1d[jj] * pv;
            lg1 += w1d[7 + jj] * pv;
            lg2 += w1d[14 + jj] * pv;
        }
        lg0 *= PSCALE; lg1 *= PSCALE; lg2 *= PSCALE;
        float mx = fmaxf(lg0, fmaxf(lg1, lg2));
        float e0 = __expf(lg0 - mx), e1 = __expf(lg1 - mx), e2 = __expf(lg2 - mx);
        float inv = 1.f / (e0 + e1 + e2);
        kk[0] = e0 * inv; kk[1] = e1 * inv; kk[2] = e2 * inv;
    }
    __syncthreads();
    float k0 = kk[0], k1 = kk[1], k2 = kk[2];

    int w0 = (i4 & 15) * 4;
    const float4 x4  = *(const float4*)(x  + (size_t)i4 * 4);
    const float4 s1v = *(const float4*)(s1 + ((size_t)(b * CC + c)) * WW + w0);
    const float  s2v = s2[rest];                  // [B,C,H] — index in hand
    const float4 s3v = *(const float4*)(s3 + ((size_t)(b * HH + h)) * WW + w0);

    float4 o;
    o.x = x4.x * (k0 * s1v.x + k1 * s2v + k2 * s3v.x);
    o.y = x4.y * (k0 * s1v.y + k1 * s2v + k2 * s3v.y);
    o.z = x4.z * (k0 * s1v.z + k1 * s2v + k2 * s3v.z);
    o.w = x4.w * (k0 * s1v.w + k1 * s2v + k2 * s3v.w);
    *(float4*)(out + (size_t)i4 * 4) = o;
}

// ---------------------------------------------------------------------------
extern "C" void kernel_launch(void* const* d_in, const int* in_sizes, int n_in,
                              void* d_out, int out_size, void* d_ws, size_t ws_size,
                              hipStream_t stream)
{
    const float* x    = (const float*)d_in[0];
    const float* w_cw = (const float*)d_in[1];
    const float* g_cw = (const float*)d_in[2];
    const float* b_cw = (const float*)d_in[3];
    const float* m_cw = (const float*)d_in[4];
    const float* v_cw = (const float*)d_in[5];
    const float* w_hc = (const float*)d_in[6];
    const float* g_hc = (const float*)d_in[7];
    const float* b_hc = (const float*)d_in[8];
    const float* m_hc = (const float*)d_in[9];
    const float* v_hc = (const float*)d_in[10];
    const float* w_hw = (const float*)d_in[11];
    const float* g_hw = (const float*)d_in[12];
    const float* b_hw = (const float*)d_in[13];
    const float* m_hw = (const float*)d_in[14];
    const float* v_hw = (const float*)d_in[15];
    const float* w1d  = (const float*)d_in[16];
    float* out = (float*)d_out;

    float* ws = (float*)d_ws;
    const size_t N1 = (size_t)BB * CC * WW;   // 131072  [B,C,W]
    const size_t N2 = (size_t)BB * CC * HH;   // 131072  [B,C,H] (transposed)
    const size_t N3 = (size_t)BB * HH * WW;   // 32768   [B,H,W]
    float* z1max   = ws;
    float* z1mean  = z1max   + N1;
    float* z2tmax  = z1mean  + N1;
    float* z2tmean = z2tmax  + N2;
    float* z3max   = z2tmean + N2;
    float* z3mean  = z3max   + N3;
    float* s1      = z3mean  + N3;
    float* s2      = s1 + N1;
    float* s3      = s2 + N2;
    float* pooled  = s3 + N3;                 // B*C = 2048 raw sums

    pool_kernel<<<BB * CC + BB * HH, 256, 0, stream>>>(
        x, z1max, z1mean, z2tmax, z2tmean, z3max, z3mean, pooled);

    gate_kernel<<<128 + BB * HH, 256, 0, stream>>>(
        x,
        z1max, z1mean, w_cw, g_cw, b_cw, m_cw, v_cw, s1,
        z2tmax, z2tmean, w_hc, g_hc, b_hc, m_hc, v_hc, s2,
        z3max, z3mean, w_hw, g_hw, b_hw, m_hw, v_hw, s3,
        pooled);

    final_kernel<<<(BB * CC * HH * WW / 4) / 256, 256, 0, stream>>>(
        x, s1, s2, s3, pooled, w1d, out);
}